// Round 6
// baseline (2849.457 us; speedup 1.0000x reference)
//
#include <hip/hip_runtime.h>
#include <hip/hip_bf16.h>
#include <stdint.h>

#define BB   128
#define TT   512
#define DIN  512
#define HH   1024
#define GG   4096
#define KTOT 1536
#define OUTD 256
#define NWG  256
#define NTHR 512

typedef __bf16 bf16x8 __attribute__((ext_vector_type(8)));
typedef float f32x4 __attribute__((ext_vector_type(4)));
typedef unsigned short u16x8 __attribute__((ext_vector_type(8)));
typedef unsigned long long u64;

__device__ __forceinline__ unsigned short f2bf(float f) {
  unsigned int u = __float_as_uint(f);
  u += 0x7fffu + ((u >> 16) & 1u);
  return (unsigned short)(u >> 16);
}
__device__ __forceinline__ float bf2f(unsigned short s) {
  return __uint_as_float(((unsigned int)s) << 16);
}

// ---- prep: Wc[g][k] bf16 = concat(W_ih[g][:], W_hh[g][:]) along k ----------
__global__ __launch_bounds__(256) void prep_wcat(const float* __restrict__ Wih,
                                                 const float* __restrict__ Whh,
                                                 unsigned short* __restrict__ Wc) {
  const int KC = KTOT / 8;
  size_t n = (size_t)GG * KC;
  for (size_t idx = (size_t)blockIdx.x * blockDim.x + threadIdx.x; idx < n;
       idx += (size_t)gridDim.x * blockDim.x) {
    int g = (int)(idx / KC);
    int k = (int)(idx % KC) * 8;
    const float* src = (k < DIN) ? (Wih + (size_t)g * DIN + k)
                                 : (Whh + (size_t)g * HH + (k - DIN));
    float4 a = *(const float4*)src;
    float4 b = *(const float4*)(src + 4);
    u16x8 o;
    o[0] = f2bf(a.x); o[1] = f2bf(a.y); o[2] = f2bf(a.z); o[3] = f2bf(a.w);
    o[4] = f2bf(b.x); o[5] = f2bf(b.y); o[6] = f2bf(b.z); o[7] = f2bf(b.w);
    *(u16x8*)(Wc + idx * 8) = o;
  }
}

// ---- persistent LSTM -------------------------------------------------------
// h ring: hfr[4 slot][4 m][128 kc][32 row][8 bf16] (fragment order, sc1/LLC)
// flags[4 m][64 n][8 wv]: producer wave wv of WG(m,n) stores t+1 after its
//   own h(t+1) slice is drained to LLC (s_waitcnt vmcnt(0)).
__global__ __launch_bounds__(NTHR, 2) void lstm_persist(
    const float* __restrict__ x,            // [B][T][DIN] f32
    const unsigned short* __restrict__ Wc,  // [GG][KTOT] bf16
    const float* __restrict__ bih,
    const float* __restrict__ bhh,
    unsigned short* __restrict__ hfr,
    unsigned int* __restrict__ flags) {
  __shared__ __align__(16) unsigned char LS[65536];  // 8-wave partials

  const int bid = blockIdx.x;
  const int m = (bid & 7) >> 1;                    // batch tile 0..3
  const int n = ((bid >> 3) << 1) | (bid & 1);     // dim group 0..63
  const int tid = threadIdx.x;
  const int wv = tid >> 6;                         // wave = K-octant
  const int lane = tid & 63;
  const int l16 = lane & 15;
  const int lk = lane >> 4;
  const int b0 = m * 32;

  // ---- preload B-fragments: slots 0-1 = x-part, 2-5 = h-part --------------
  bf16x8 wreg[6][4];
#pragma unroll
  for (int nt = 0; nt < 4; ++nt) {
    const unsigned short* wrow = Wc + (size_t)(nt * HH + n * 16 + l16) * KTOT;
#pragma unroll
    for (int kk = 0; kk < 2; ++kk)
      wreg[kk][nt] = *(const bf16x8*)(wrow + wv * 64 + kk * 32 + lk * 8);
#pragma unroll
    for (int kk = 2; kk < 6; ++kk)
      wreg[kk][nt] = *(const bf16x8*)(wrow + 512 + wv * 128 + (kk - 2) * 32 + lk * 8);
  }

  // ---- per-thread cell element -------------------------------------------
  const int ml = tid >> 4, dd = tid & 15;
  const int kg = n * 16 + dd;
  const float bi_ = bih[0 * HH + kg] + bhh[0 * HH + kg];
  const float bf_ = bih[1 * HH + kg] + bhh[1 * HH + kg];
  const float bg_ = bih[2 * HH + kg] + bhh[2 * HH + kg];
  const float bo_ = bih[3 * HH + kg] + bhh[3 * HH + kg];
  float cst = 0.f;
  const int gbo = (ml >> 4) * 256 + (((ml & 15) >> 2) * 16 + dd) * 4 + (ml & 3);
  const unsigned hso = (unsigned)(((n * 2 + (dd >> 3)) * 32 + ml) * 8 + (dd & 7));
  unsigned int* grpf = flags + m * 512;
  const unsigned int* pollf = grpf + 64 * wv;      // +lane = my 64 producer waves

  f32x4 acc[4][2];
  bf16x8 xaf[2][2];

  auto xload = [&](int rt) {
#pragma unroll
    for (int kk = 0; kk < 2; ++kk)
#pragma unroll
      for (int mf = 0; mf < 2; ++mf) {
        const float* src = x + ((size_t)(b0 + mf * 16 + l16) * TT + rt) * DIN +
                           wv * 64 + kk * 32 + lk * 8;
        float4 a = *(const float4*)src;
        float4 b = *(const float4*)(src + 4);
        u16x8 v;
        v[0] = f2bf(a.x); v[1] = f2bf(a.y); v[2] = f2bf(a.z); v[3] = f2bf(a.w);
        v[4] = f2bf(b.x); v[5] = f2bf(b.y); v[6] = f2bf(b.z); v[7] = f2bf(b.w);
        xaf[kk][mf] = (bf16x8)v;
      }
  };
  auto xmfma = [&]() {
#pragma unroll
    for (int nt = 0; nt < 4; ++nt) {
      acc[nt][0] = (f32x4){0.f, 0.f, 0.f, 0.f};
      acc[nt][1] = (f32x4){0.f, 0.f, 0.f, 0.f};
    }
#pragma unroll
    for (int kk = 0; kk < 2; ++kk)
#pragma unroll
      for (int mf = 0; mf < 2; ++mf)
#pragma unroll
        for (int nt = 0; nt < 4; ++nt)
          acc[nt][mf] = __builtin_amdgcn_mfma_f32_16x16x32_bf16(
              xaf[kk][mf], wreg[kk][nt], acc[nt][mf], 0, 0, 0);
  };

  xload(TT - 1);
  xmfma();

#pragma unroll 1
  for (int t = 0;; ) {
    // ---- poll my 64 producer waves for h(t) (pure relaxed sc1) -----------
    {
      const unsigned tgt = (unsigned)t;
      while (true) {
        unsigned v = __hip_atomic_load(&pollf[lane], __ATOMIC_RELAXED,
                                       __HIP_MEMORY_SCOPE_AGENT);
        if (__all(v >= tgt)) break;
      }
    }

    // ---- batch-issue all 16 h fragment loads, then MFMA ------------------
    {
      const unsigned short* hs = hfr + (size_t)(t & 3) * 131072 + m * 32768;
      u64 hq[16];
#pragma unroll
      for (int kk = 0; kk < 4; ++kk) {
        int kc = wv * 16 + kk * 4 + lk;
#pragma unroll
        for (int mf = 0; mf < 2; ++mf) {
          const u64* p = (const u64*)(hs + ((size_t)kc * 32 + mf * 16 + l16) * 8);
          hq[(kk * 2 + mf) * 2 + 0] =
              __hip_atomic_load(p, __ATOMIC_RELAXED, __HIP_MEMORY_SCOPE_AGENT);
          hq[(kk * 2 + mf) * 2 + 1] =
              __hip_atomic_load(p + 1, __ATOMIC_RELAXED, __HIP_MEMORY_SCOPE_AGENT);
        }
      }
#pragma unroll
      for (int kk = 0; kk < 4; ++kk)
#pragma unroll
        for (int mf = 0; mf < 2; ++mf) {
          union { u64 q[2]; bf16x8 v; } c;
          c.q[0] = hq[(kk * 2 + mf) * 2 + 0];
          c.q[1] = hq[(kk * 2 + mf) * 2 + 1];
#pragma unroll
          for (int nt = 0; nt < 4; ++nt)
            acc[nt][mf] = __builtin_amdgcn_mfma_f32_16x16x32_bf16(
                c.v, wreg[kk + 2][nt], acc[nt][mf], 0, 0, 0);
        }
    }

    // ---- partials to LDS (distinct slots), one sync ----------------------
#pragma unroll
    for (int nt = 0; nt < 4; ++nt)
#pragma unroll
      for (int mf = 0; mf < 2; ++mf)
        *(f32x4*)(LS + ((((wv * 4 + nt) * 2 + mf) * 64) + lane) * 16) = acc[nt][mf];
    __syncthreads();  // S1

    // ---- gather 8-way K-partials + cell update ---------------------------
    float g0 = 0.f, g1 = 0.f, g2 = 0.f, g3 = 0.f;
    const float* P = (const float*)LS;
#pragma unroll
    for (int w = 0; w < 8; ++w) {
      g0 += P[gbo + (w * 4 + 0) * 512];
      g1 += P[gbo + (w * 4 + 1) * 512];
      g2 += P[gbo + (w * 4 + 2) * 512];
      g3 += P[gbo + (w * 4 + 3) * 512];
    }
    float gi = g0 + bi_, gf = g1 + bf_, gg = g2 + bg_, go = g3 + bo_;
    float si = 1.f / (1.f + __expf(-gi));
    float sf = 1.f / (1.f + __expf(-gf));
    float tg = tanhf(gg);
    float so = 1.f / (1.f + __expf(-go));
    cst = sf * cst + si * tg;

    // ---- publish h(t+1) (paired dword, sc1) ------------------------------
    unsigned hv = (unsigned)f2bf(so * tanhf(cst));
    unsigned other = (unsigned)__shfl_xor((int)hv, 1);
    if (!(dd & 1)) {
      unsigned dword = hv | (other << 16);
      unsigned short* dst = hfr + (size_t)((t + 1) & 3) * 131072 + m * 32768 + hso;
      __hip_atomic_store((unsigned*)dst, dword, __ATOMIC_RELAXED,
                         __HIP_MEMORY_SCOPE_AGENT);
    }
    // per-wave flag: own publish drained to LLC, then announce
    asm volatile("s_waitcnt vmcnt(0)" ::: "memory");
    if (lane == 0)
      __hip_atomic_store(&grpf[n * 8 + wv], (unsigned)(t + 1), __ATOMIC_RELAXED,
                         __HIP_MEMORY_SCOPE_AGENT);

    if (t == TT - 1) break;

    __syncthreads();  // S2: all gathers done before next partial write

    // ---- shadow: x fragments + x-part MFMA for t+1 -----------------------
    ++t;
    xload(TT - 1 - t);
    xmfma();
  }
}

// ---- out = h_final @ W_out^T + b_out; h read from frag layout (sc1) --------
__global__ __launch_bounds__(256) void out_proj(const unsigned short* __restrict__ hfr,
                                                const float* __restrict__ Wout,
                                                const float* __restrict__ bout,
                                                float* __restrict__ out) {
  __shared__ float hs[HH];
  int b = blockIdx.x;
  int tid = threadIdx.x;
  const unsigned short* hb = hfr + (size_t)(b >> 5) * 32768;  // slot 0
  for (int kc = tid; kc < 128; kc += 256) {
    const u64* p = (const u64*)(hb + ((size_t)kc * 32 + (b & 31)) * 8);
    u64 lo = __hip_atomic_load(p, __ATOMIC_RELAXED, __HIP_MEMORY_SCOPE_AGENT);
    u64 hi = __hip_atomic_load(p + 1, __ATOMIC_RELAXED, __HIP_MEMORY_SCOPE_AGENT);
#pragma unroll
    for (int j = 0; j < 4; ++j) {
      hs[kc * 8 + j] = bf2f((unsigned short)(lo >> (16 * j)));
      hs[kc * 8 + 4 + j] = bf2f((unsigned short)(hi >> (16 * j)));
    }
  }
  __syncthreads();
  const float* wr = Wout + (size_t)tid * HH;
  float acc = bout[tid];
#pragma unroll 4
  for (int k = 0; k < HH; k += 4) {
    float4 wv = *(const float4*)(wr + k);
    acc += hs[k] * wv.x + hs[k + 1] * wv.y + hs[k + 2] * wv.z + hs[k + 3] * wv.w;
  }
  out[(size_t)b * OUTD + tid] = acc;
}

extern "C" void kernel_launch(void* const* d_in, const int* in_sizes, int n_in,
                              void* d_out, int out_size, void* d_ws, size_t ws_size,
                              hipStream_t stream) {
  const float* x    = (const float*)d_in[0];
  const float* Wih  = (const float*)d_in[1];
  const float* Whh  = (const float*)d_in[2];
  const float* bih  = (const float*)d_in[3];
  const float* bhh  = (const float*)d_in[4];
  const float* Wout = (const float*)d_in[5];
  const float* bout = (const float*)d_in[6];
  float* out = (float*)d_out;

  uint8_t* w = (uint8_t*)d_ws;
  unsigned short* Wc    = (unsigned short*)(w);             // 12,582,912 B
  unsigned short* hfr   = (unsigned short*)(w + 12582912);  // 4 slots x 262,144 B
  unsigned int*   flags = (unsigned int*)(w + 13631488);    // 8,192 B

  hipMemsetAsync(hfr, 0, 262144, stream);   // slot 0 = h(0) = 0
  hipMemsetAsync(flags, 0, 8192, stream);
  prep_wcat<<<1024, 256, 0, stream>>>(Wih, Whh, Wc);

  void* args[] = {(void*)&x, (void*)&Wc, (void*)&bih, (void*)&bhh,
                  (void*)&hfr, (void*)&flags};
  hipLaunchCooperativeKernel((const void*)lstm_persist, dim3(NWG), dim3(NTHR),
                             args, 0, stream);

  // h(512) lives in ring slot 512&3 = 0
  out_proj<<<BB, 256, 0, stream>>>(hfr, Wout, bout, out);
}